// Round 10
// baseline (374.648 us; speedup 1.0000x reference)
//
#include <hip/hip_runtime.h>

// MultiHeadAttention: B=2, S=2048, D=1024, H=16, HD=64, scores MULTIPLIED by 64.
// Round 17: R16 FAILED (absmax 2.89) — fused cross-workgroup merge read the
// other block's Op/ml via plain stores + threadfence: Guideline-16 hazard
// (per-XCD L2 / L1 staleness). REVERTED to separate merge kernel. Kept the two
// safe R16 deltas: (1) fp16 Op partials (halves Op write+read traffic;
// numerics validated R14/R15), (2) exact defer-max (skip rescale when
// __all(rmax<=m): elides *1.0 only, bit-identical, wave-uniform branch).
// 4 launches: convert_all, proj3, flash, merge.
// LDS image: row r, logical chunk c stored at col (c ^ (r&7)) -- 2-way banks (free).
// Workspace 100 MiB: 0 qh_hi | 8 qh_lo | 16 kh_hi | 24 kh_lo | 32 vhT |
//   40..56 Op (fp16 x2, aliases dead slots) | 48 xq_h | 56 xq_l | 64 xk_h |
//   72 xk_l | 80 xv_h | 88..98 W* | 98..99 ml.

typedef _Float16 half4 __attribute__((ext_vector_type(4)));
typedef _Float16 half8 __attribute__((ext_vector_type(8)));
typedef float floatx4 __attribute__((ext_vector_type(4)));

#define MFMA_F16(a, b, c) __builtin_amdgcn_mfma_f32_16x16x32_f16((a), (b), (c), 0, 0, 0)

constexpr int SEQ = 2048;
constexpr int DM = 1024;
constexpr int NH = 16;
constexpr int HD = 64;
// 64 * log2(e): fold score scale + base-2 conversion into Q projection
constexpr float QSCALE = 92.33248261689366f;

// async 16B/lane global->LDS copy; LDS dest = wave-uniform base + lane*16
__device__ __forceinline__ void gl2lds16(const _Float16* g, _Float16* l) {
  __builtin_amdgcn_global_load_lds(
      (const __attribute__((address_space(1))) void*)g,
      (__attribute__((address_space(3))) void*)l, 16, 0, 0);
}

__device__ inline void split4(const float4 f, half4& h, half4& l) {
  h[0] = (_Float16)f.x; l[0] = (_Float16)(f.x - (float)h[0]);
  h[1] = (_Float16)f.y; l[1] = (_Float16)(f.y - (float)h[1]);
  h[2] = (_Float16)f.z; l[2] = (_Float16)(f.z - (float)h[2]);
  h[3] = (_Float16)f.w; l[3] = (_Float16)(f.w - (float)h[3]);
}

// ---------------- fused convert: all six fp32 tensors -> fp16 hi (+lo) ------
__global__ __launch_bounds__(256) void convert_all(
    const float* __restrict__ q, const float* __restrict__ k,
    const float* __restrict__ v, const float* __restrict__ Wq,
    const float* __restrict__ Wk, const float* __restrict__ Wv,
    _Float16* __restrict__ xq_h, _Float16* __restrict__ xq_l,
    _Float16* __restrict__ xk_h, _Float16* __restrict__ xk_l,
    _Float16* __restrict__ xv_h,
    _Float16* __restrict__ Wqh, _Float16* __restrict__ Wql,
    _Float16* __restrict__ Wkh, _Float16* __restrict__ Wkl,
    _Float16* __restrict__ Wvh)
{
  const int bid = blockIdx.x;
  const float* src; _Float16* dh; _Float16* dl; int do_lo, i0;
  if (bid < 4096)       { src = q;  dh = xq_h; dl = xq_l; do_lo = 1; i0 = bid; }
  else if (bid < 8192)  { src = k;  dh = xk_h; dl = xk_l; do_lo = 1; i0 = bid - 4096; }
  else if (bid < 12288) { src = v;  dh = xv_h; dl = xv_h; do_lo = 0; i0 = bid - 8192; }
  else if (bid < 13312) { src = Wq; dh = Wqh;  dl = Wql;  do_lo = 1; i0 = bid - 12288; }
  else if (bid < 14336) { src = Wk; dh = Wkh;  dl = Wkl;  do_lo = 1; i0 = bid - 13312; }
  else                  { src = Wv; dh = Wvh;  dl = Wvh;  do_lo = 0; i0 = bid - 14336; }
  const int idx = i0 * 256 + threadIdx.x;
  float4 f = ((const float4*)src)[idx];
  half4 h, l; split4(f, h, l);
  *(half4*)(dh + (size_t)idx * 4) = h;
  if (do_lo) *(half4*)(dl + (size_t)idx * 4) = l;
}

// ---------------- fused projection GEMMs: y = A @ B^T (pre-converted fp16) --
// 128x128 tile, BK=64, global_load_lds staging, single-buffered (64 KiB LDS ->
// 2 blocks/CU). Grid (32,8,3): z selects {Q,K,V}. Q/K: 3-term split-fp16,
// scalar hi/lo epilogue. V: single-term, epilogue writes vhT directly in the
// flash-permuted transposed layout.
__global__ __launch_bounds__(256, 1) void proj3_kernel(
    const _Float16* __restrict__ xq_h, const _Float16* __restrict__ xq_l,
    const _Float16* __restrict__ xk_h, const _Float16* __restrict__ xk_l,
    const _Float16* __restrict__ xv_h,
    const _Float16* __restrict__ Wqh, const _Float16* __restrict__ Wql,
    const _Float16* __restrict__ Wkh, const _Float16* __restrict__ Wkl,
    const _Float16* __restrict__ Wvh,
    _Float16* __restrict__ qh_hi, _Float16* __restrict__ qh_lo,
    _Float16* __restrict__ kh_hi, _Float16* __restrict__ kh_lo,
    _Float16* __restrict__ vhT)
{
  __shared__ __align__(16) _Float16 Ahs[128][64];
  __shared__ __align__(16) _Float16 Als[128][64];
  __shared__ __align__(16) _Float16 Bhs[128][64];
  __shared__ __align__(16) _Float16 Bls[128][64];

  const int z = blockIdx.z;
  const _Float16 *Ahg, *Alg, *Bhg, *Blg;
  _Float16 *yh, *yl;
  float scale; int three;
  if (z == 0)      { Ahg = xq_h; Alg = xq_l; Bhg = Wqh; Blg = Wql;
                     yh = qh_hi; yl = qh_lo; scale = QSCALE; three = 1; }
  else if (z == 1) { Ahg = xk_h; Alg = xk_l; Bhg = Wkh; Blg = Wkl;
                     yh = kh_hi; yl = kh_lo; scale = 1.0f; three = 1; }
  else             { Ahg = xv_h; Alg = xv_h; Bhg = Wvh; Blg = Wvh;
                     yh = vhT;   yl = vhT;   scale = 1.0f; three = 0; }

  const int tid = threadIdx.x;
  const int bm = blockIdx.x;          // 0..31
  const int bn = blockIdx.y;          // 0..7
  const int lane = tid & 63, l15 = lane & 15, quad = lane >> 4;
  const int w = tid >> 6, wm = w >> 1, wn = w & 1;

  // staging: wave w stages groups g = 4w+i (8 rows x 1 KiB each) of each array.
  const int r8 = lane >> 3;
  const int cp8 = (((lane & 7) ^ r8)) * 8;
  int grow_[4]; _Float16* la[4]; _Float16* lal[4]; _Float16* lb[4]; _Float16* lbl[4];
  #pragma unroll
  for (int i = 0; i < 4; i++) {
    const int g = w * 4 + i;
    grow_[i] = g * 8 + r8;
    la[i]  = &Ahs[0][0] + g * 512;
    lal[i] = &Als[0][0] + g * 512;
    lb[i]  = &Bhs[0][0] + g * 512;
    lbl[i] = &Bls[0][0] + g * 512;
  }

  floatx4 acc[4][4];
  #pragma unroll
  for (int mt = 0; mt < 4; mt++)
    #pragma unroll
    for (int nt = 0; nt < 4; nt++)
      acc[mt][nt] = (floatx4){0.f, 0.f, 0.f, 0.f};

  for (int kk = 0; kk < DM; kk += 64) {
    __syncthreads();
    #pragma unroll
    for (int i = 0; i < 4; i++) {
      const size_t ga = (size_t)(bm * 128 + grow_[i]) * DM + kk + cp8;
      const size_t gb = (size_t)(bn * 128 + grow_[i]) * DM + kk + cp8;
      gl2lds16(Ahg + ga, la[i]);
      gl2lds16(Bhg + gb, lb[i]);
      if (three) {
        gl2lds16(Alg + ga, lal[i]);
        gl2lds16(Blg + gb, lbl[i]);
      }
    }
    __syncthreads();

    #pragma unroll
    for (int kc = 0; kc < 2; kc++) {
      const int swz = ((kc * 4 + quad) ^ (l15 & 7)) * 8;
      half8 ah[4], bh_[4], al[4], bl[4];
      #pragma unroll
      for (int t = 0; t < 4; t++) {
        ah[t]  = *(const half8*)&Ahs[wm * 64 + t * 16 + l15][swz];
        bh_[t] = *(const half8*)&Bhs[wn * 64 + t * 16 + l15][swz];
        if (three) {
          al[t] = *(const half8*)&Als[wm * 64 + t * 16 + l15][swz];
          bl[t] = *(const half8*)&Bls[wn * 64 + t * 16 + l15][swz];
        }
      }
      if (three) {
        #pragma unroll
        for (int mt = 0; mt < 4; mt++)
          #pragma unroll
          for (int nt = 0; nt < 4; nt++) {
            floatx4 t0 = MFMA_F16(ah[mt], bh_[nt], acc[mt][nt]);
            t0 = MFMA_F16(ah[mt], bl[nt], t0);
            acc[mt][nt] = MFMA_F16(al[mt], bh_[nt], t0);
          }
      } else {
        #pragma unroll
        for (int mt = 0; mt < 4; mt++)
          #pragma unroll
          for (int nt = 0; nt < 4; nt++)
            acc[mt][nt] = MFMA_F16(ah[mt], bh_[nt], acc[mt][nt]);
      }
    }
  }

  if (three) {
    // Q/K epilogue: scalar hi/lo stores to [b,h,s,d]
    #pragma unroll
    for (int mt = 0; mt < 4; mt++)
      #pragma unroll
      for (int nt = 0; nt < 4; nt++)
        #pragma unroll
        for (int r = 0; r < 4; r++) {
          int gm = bm * 128 + wm * 64 + mt * 16 + quad * 4 + r;   // (b,s)
          int gn = bn * 128 + wn * 64 + nt * 16 + l15;            // h*64+d
          int b = gm >> 11, s = gm & 2047;
          int h = gn >> 6, d = gn & 63;
          size_t idx = ((size_t)(b * NH + h) * SEQ + s) * HD + d;
          float val = acc[mt][nt][r] * scale;
          _Float16 hi = (_Float16)val;
          yh[idx] = hi;
          yl[idx] = (_Float16)(val - (float)hi);
        }
  } else {
    // V epilogue: write vhT [bh][d][perm(s)] directly (half4 per (mt,nt)).
    // perm: 16a+4q+b -> 8q+4a+b, so pos = sbase + (mt>>1)*32 + quad*8 + (mt&1)*4 + r
    const int b = bm >> 4;
    const int h = bn * 2 + wn;
    const int bh = b * NH + h;
    const int sbase = (bm & 15) * 128 + wm * 64;
    _Float16* vt = vhT + (size_t)bh * HD * SEQ;
    #pragma unroll
    for (int mt = 0; mt < 4; mt++) {
      const int pos = sbase + (mt >> 1) * 32 + quad * 8 + (mt & 1) * 4;
      #pragma unroll
      for (int nt = 0; nt < 4; nt++) {
        const int d = nt * 16 + l15;
        half4 hv;
        hv[0] = (_Float16)acc[mt][nt][0];
        hv[1] = (_Float16)acc[mt][nt][1];
        hv[2] = (_Float16)acc[mt][nt][2];
        hv[3] = (_Float16)acc[mt][nt][3];
        *(half4*)(vt + (size_t)d * SEQ + pos) = hv;
      }
    }
  }
}

// ---------------- flash attention v17: R12 body + defer-max + fp16 Op ------
// 1-D grid 1024; bh = (id&7) + 8*((id>>3)&3) pins each bh's K/V to one XCD L2.
// 4 waves, 32 q/wave. K hi/lo double-buffered, V single (40960 B LDS).
// Per kt: barrier -> stage V(kt)+K(kt+1) -> QK^T+softmax+pack -> barrier(drain)
// -> av reads + PV. Defer-max: __all(rmax<=m) -> skip alpha/rescale (exact).
__global__ __launch_bounds__(256, 4) void flash_kernel(
    const _Float16* __restrict__ qh_hi, const _Float16* __restrict__ qh_lo,
    const _Float16* __restrict__ kh_hi, const _Float16* __restrict__ kh_lo,
    const _Float16* __restrict__ vhT, _Float16* __restrict__ Op,
    float2* __restrict__ ml)
{
  __shared__ __align__(16) _Float16 Kh[2][64][64];
  __shared__ __align__(16) _Float16 Kl[2][64][64];
  __shared__ __align__(16) _Float16 Vt[64][64];   // [d][permuted key]

  const int id = blockIdx.x;
  const int seq_ = id >> 3;
  const int bh = (id & 7) + 8 * (seq_ & 3);       // 0..31, pinned to XCD id&7
  const int rem = seq_ >> 2;
  const int qb = rem & 15;                        // 0..15
  const int kh = rem >> 4;                        // 0..1
  const int tid = threadIdx.x;
  const int wq = tid >> 6;
  const int lane = tid & 63, l15 = lane & 15, quad = lane >> 4;

  const size_t bh_off = (size_t)bh * SEQ * HD;
  const _Float16* __restrict__ kh_p = kh_hi + bh_off;
  const _Float16* __restrict__ kl_p = kh_lo + bh_off;
  const _Float16* __restrict__ vt_p = vhT + (size_t)bh * HD * SEQ;
  const int qrow0 = qb * 128 + wq * 32;

  // Q as B-operand fragments: lane holds n=q=l15, k=d=kc*32+quad*8+j
  half8 bqh[2][2], bql[2][2];         // [g][kc]
  #pragma unroll
  for (int g = 0; g < 2; g++) {
    const _Float16* qp_h = qh_hi + bh_off + (size_t)(qrow0 + g * 16 + l15) * HD;
    const _Float16* qp_l = qh_lo + bh_off + (size_t)(qrow0 + g * 16 + l15) * HD;
    #pragma unroll
    for (int kc = 0; kc < 2; kc++) {
      bqh[g][kc] = *(const half8*)(qp_h + kc * 32 + quad * 8);
      bql[g][kc] = *(const half8*)(qp_l + kc * 32 + quad * 8);
    }
  }

  // staging: wave wq covers groups 2wq, 2wq+1 per array (8 rows x 1 KiB each)
  const int r8 = lane >> 3;
  const int cp8 = ((lane & 7) ^ r8) * 8;

  float m_[2] = {-3.0e38f, -3.0e38f};
  float l_[2] = {0.f, 0.f};
  floatx4 Oacc[2][4];
  #pragma unroll
  for (int g = 0; g < 2; g++)
    #pragma unroll
    for (int nd = 0; nd < 4; nd++) Oacc[g][nd] = (floatx4){0.f, 0.f, 0.f, 0.f};

  const int kt0 = kh * 16;
  // prologue: stage K(kt0) into buffer 0
  {
    const int kbase = kt0 * 64;
    #pragma unroll
    for (int i = 0; i < 2; i++) {
      const int g = wq * 2 + i;
      const int r = g * 8 + r8;
      gl2lds16(kh_p + (size_t)(kbase + r) * HD + cp8, &Kh[0][0][0] + g * 512);
      gl2lds16(kl_p + (size_t)(kbase + r) * HD + cp8, &Kl[0][0][0] + g * 512);
    }
  }

  for (int kt = kt0; kt < kt0 + 16; kt++) {
    const int cur = kt & 1;                     // kt0 even -> prologue in buf 0
    const int kbase = kt * 64;
    __syncthreads();            // K(kt) visible; Vt free; Kbuf[cur^1] free

    // stage V(kt) and prefetch K(kt+1); both drain at the mid barrier below
    #pragma unroll
    for (int i = 0; i < 2; i++) {
      const int g = wq * 2 + i;
      const int r = g * 8 + r8;
      gl2lds16(vt_p + (size_t)r * SEQ + kbase + cp8, &Vt[0][0] + g * 512);
    }
    if (kt + 1 < kt0 + 16) {
      const int kb2 = (kt + 1) * 64, nxt = cur ^ 1;
      #pragma unroll
      for (int i = 0; i < 2; i++) {
        const int g = wq * 2 + i;
        const int r = g * 8 + r8;
        gl2lds16(kh_p + (size_t)(kb2 + r) * HD + cp8, &Kh[nxt][0][0] + g * 512);
        gl2lds16(kl_p + (size_t)(kb2 + r) * HD + cp8, &Kl[nxt][0][0] + g * 512);
      }
    }

    // S^T = K·Q^T (3-term split fp16), both q-groups share K fragments
    floatx4 sacc[2][4];
    const int r7 = l15 & 7;
    #pragma unroll
    for (int nt = 0; nt < 4; nt++) {
      half8 akh0 = *(const half8*)&Kh[cur][nt * 16 + l15][((0 * 4 + quad) ^ r7) * 8];
      half8 akh1 = *(const half8*)&Kh[cur][nt * 16 + l15][((1 * 4 + quad) ^ r7) * 8];
      half8 akl0 = *(const half8*)&Kl[cur][nt * 16 + l15][((0 * 4 + quad) ^ r7) * 8];
      half8 akl1 = *(const half8*)&Kl[cur][nt * 16 + l15][((1 * 4 + quad) ^ r7) * 8];
      #pragma unroll
      for (int g = 0; g < 2; g++) {
        floatx4 s4 = (floatx4){0.f, 0.f, 0.f, 0.f};
        s4 = MFMA_F16(akh0, bqh[g][0], s4);
        s4 = MFMA_F16(akh1, bqh[g][1], s4);
        s4 = MFMA_F16(akh0, bql[g][0], s4);
        s4 = MFMA_F16(akh1, bql[g][1], s4);
        s4 = MFMA_F16(akl0, bqh[g][0], s4);
        s4 = MFMA_F16(akl1, bqh[g][1], s4);
        sacc[g][nt] = s4;
      }
    }

    // online softmax + P pack for BOTH q-groups (before the drain barrier).
    // Defer-max: if no row's max grew, alpha==1 exactly -> skip rescale.
    bool skipg[2];
    float alpha2[2];
    half8 bp8g[2][2];
    #pragma unroll
    for (int g = 0; g < 2; g++) {
      float rmax = sacc[g][0][0];
      #pragma unroll
      for (int nt = 0; nt < 4; nt++)
        #pragma unroll
        for (int r = 0; r < 4; r++) rmax = fmaxf(rmax, sacc[g][nt][r]);
      rmax = fmaxf(rmax, __shfl_xor(rmax, 16, 64));
      rmax = fmaxf(rmax, __shfl_xor(rmax, 32, 64));
      const bool grown = __any(rmax > m_[g]);
      skipg[g] = !grown;
      if (grown) {
        const float mnew = fmaxf(m_[g], rmax);
        alpha2[g] = exp2f(m_[g] - mnew);
        m_[g] = mnew;
      } else {
        alpha2[g] = 1.0f;
      }

      float rsum = 0.f;
      #pragma unroll
      for (int nt = 0; nt < 4; nt++)
        #pragma unroll
        for (int r = 0; r < 4; r++) {
          float p = exp2f(sacc[g][nt][r] - m_[g]);
          sacc[g][nt][r] = p;
          rsum += p;
        }
      rsum += __shfl_xor(rsum, 16, 64);
      rsum += __shfl_xor(rsum, 32, 64);
      l_[g] = skipg[g] ? (l_[g] + rsum) : (l_[g] * alpha2[g] + rsum);

      // P pack for PV B-operand: bp8g[g][kc][j] = p[2kc + (j>>2)][j&3] (in-lane)
      #pragma unroll
      for (int kc = 0; kc < 2; kc++)
        #pragma unroll
        for (int j = 0; j < 8; j++)
          bp8g[g][kc][j] = (_Float16)sacc[g][2 * kc + (j >> 2)][j & 3];
    }

    __syncthreads();            // V(kt) + K(kt+1) drained & visible

    // V A-fragments (permuted image), shared by both q-groups
    half8 av[4][2];
    #pragma unroll
    for (int nd = 0; nd < 4; nd++) {
      av[nd][0] = *(const half8*)&Vt[nd * 16 + l15][((0 * 4 + quad) ^ r7) * 8];
      av[nd][1] = *(const half8*)&Vt[nd * 16 + l15][((1 * 4 + quad) ^ r7) * 8];
    }

    #pragma unroll
    for (int g = 0; g < 2; g++) {
      if (!skipg[g]) {          // wave-uniform; alpha==1 when skipped (exact)
        #pragma unroll
        for (int nd = 0; nd < 4; nd++) {
          Oacc[g][nd][0] *= alpha2[g]; Oacc[g][nd][1] *= alpha2[g];
          Oacc[g][nd][2] *= alpha2[g]; Oacc[g][nd][3] *= alpha2[g];
        }
      }
      #pragma unroll
      for (int nd = 0; nd < 4; nd++) {
        Oacc[g][nd] = MFMA_F16(av[nd][0], bp8g[g][0], Oacc[g][nd]);
        Oacc[g][nd] = MFMA_F16(av[nd][1], bp8g[g][1], Oacc[g][nd]);
      }
    }
  }

  // epilogue: unnormalized O^T partial (fp16) + (m,l)
  const size_t fqbase = (size_t)bh * SEQ + qrow0;
  #pragma unroll
  for (int g = 0; g < 2; g++) {
    const size_t fq = fqbase + g * 16 + l15;
    _Float16* ob = Op + ((size_t)kh * 65536 + fq) * HD;
    #pragma unroll
    for (int nd = 0; nd < 4; nd++) {
      half4 hv;
      hv[0] = (_Float16)Oacc[g][nd][0]; hv[1] = (_Float16)Oacc[g][nd][1];
      hv[2] = (_Float16)Oacc[g][nd][2]; hv[3] = (_Float16)Oacc[g][nd][3];
      *(half4*)(ob + nd * 16 + quad * 4) = hv;
    }
    if (quad == 0) ml[kh * 65536 + fq] = make_float2(m_[g], l_[g]);
  }
}

// ---------------- merge the two split-K partials (fp16 Op) ------------------
__global__ __launch_bounds__(256) void merge_kernel(const _Float16* __restrict__ Op,
                                                    const float2* __restrict__ ml,
                                                    float* __restrict__ out)
{
  const int tid = threadIdx.x;
  const int fq = blockIdx.x * 64 + (tid >> 2);
  const int dp = (tid & 3) * 16;
  float2 m0 = ml[fq], m1 = ml[65536 + fq];
  float M = fmaxf(m0.x, m1.x);
  float w0 = exp2f(m0.x - M), w1 = exp2f(m1.x - M);
  float rinv = 1.0f / (m0.y * w0 + m1.y * w1);
  int bh = fq >> 11, s = fq & 2047, b = bh >> 4, h = bh & 15;
  float* ob = out + ((size_t)(b * SEQ + s)) * DM + h * HD + dp;
  const _Float16* p0 = Op + (size_t)fq * HD + dp;
  const _Float16* p1 = p0 + (size_t)65536 * HD;
  #pragma unroll
  for (int j = 0; j < 4; j++) {
    half4 a = *(const half4*)(p0 + 4 * j);
    half4 c = *(const half4*)(p1 + 4 * j);
    float4 r;
    r.x = ((float)a[0] * w0 + (float)c[0] * w1) * rinv;
    r.y = ((float)a[1] * w0 + (float)c[1] * w1) * rinv;
    r.z = ((float)a[2] * w0 + (float)c[2] * w1) * rinv;
    r.w = ((float)a[3] * w0 + (float)c[3] * w1) * rinv;
    *(float4*)(ob + 4 * j) = r;
  }
}

extern "C" void kernel_launch(void* const* d_in, const int* in_sizes, int n_in,
                              void* d_out, int out_size, void* d_ws, size_t ws_size,
                              hipStream_t stream) {
  const float* q  = (const float*)d_in[0];
  const float* k  = (const float*)d_in[1];
  const float* v  = (const float*)d_in[2];
  const float* Wq = (const float*)d_in[3];
  const float* Wk = (const float*)d_in[4];
  const float* Wv = (const float*)d_in[5];
  float* out = (float*)d_out;

  char* W = (char*)d_ws;
  const size_t MiB = 1ull << 20;
  _Float16* qh_hi = (_Float16*)(W + 0 * MiB);
  _Float16* qh_lo = (_Float16*)(W + 8 * MiB);
  _Float16* kh_hi = (_Float16*)(W + 16 * MiB);
  _Float16* kh_lo = (_Float16*)(W + 24 * MiB);
  _Float16* vhT   = (_Float16*)(W + 32 * MiB);
  _Float16* xq_h  = (_Float16*)(W + 48 * MiB);  // dead after proj3
  _Float16* xq_l  = (_Float16*)(W + 56 * MiB);
  _Float16* xk_h  = (_Float16*)(W + 64 * MiB);
  _Float16* xk_l  = (_Float16*)(W + 72 * MiB);
  _Float16* xv_h  = (_Float16*)(W + 80 * MiB);
  _Float16* Wqh   = (_Float16*)(W + 88 * MiB);
  _Float16* Wql   = (_Float16*)(W + 90 * MiB);
  _Float16* Wkh   = (_Float16*)(W + 92 * MiB);
  _Float16* Wkl   = (_Float16*)(W + 94 * MiB);
  _Float16* Wvh   = (_Float16*)(W + 96 * MiB);
  _Float16* Op    = (_Float16*)(W + 40 * MiB);  // 2 x 8 MiB fp16, aliases dead slots
  float2*   mlp   = (float2*) (W + 98 * MiB);   // 1 MiB; total 99 MiB

  convert_all<<<15360, 256, 0, stream>>>(q, k, v, Wq, Wk, Wv,
                                         xq_h, xq_l, xk_h, xk_l, xv_h,
                                         Wqh, Wql, Wkh, Wkl, Wvh);
  proj3_kernel<<<dim3(32, 8, 3), 256, 0, stream>>>(
      xq_h, xq_l, xk_h, xk_l, xv_h, Wqh, Wql, Wkh, Wkl, Wvh,
      qh_hi, qh_lo, kh_hi, kh_lo, vhT);
  flash_kernel<<<1024, 256, 0, stream>>>(qh_hi, qh_lo, kh_hi, kh_lo, vhT, Op, mlp);
  merge_kernel<<<1024, 256, 0, stream>>>(Op, mlp, out);
}

// Round 11
// 279.986 us; speedup vs baseline: 1.3381x; 1.3381x over previous
//
#include <hip/hip_runtime.h>

// MultiHeadAttention: B=2, S=2048, D=1024, H=16, HD=64, scores MULTIPLIED by 64.
// Round 18: byte-exact revert to R12 (293.2 us) — the empirical optimum.
// R13..R17 post-mortems: softmax-diet (+4us, latency-chain not VALU-bound),
// forced-occupancy 6/CU (spill, +378us), split-K x4 (L2 thrash, +7us), fused
// cross-WG merge (XCD-coherence FAIL), defer-max branch (per-iter spill around
// exec-mask joins, +81us; fp16-Op 8B stores also 2x sector-amplify writes).
// Flash's R12 config is the local optimum for this 2-barrier structure.
// LDS image: row r, logical chunk c stored at col (c ^ (r&7)) -- 2-way banks (free).
// Workspace 99 MiB: 0 qh_hi | 8 qh_lo | 16 kh_hi | 24 kh_lo | 32 vhT | 40 (Op) |
//   48 xq_h | 56 xq_l | 64 xk_h | 72 xk_l | 80 xv_h | 88 Wqh | 90 Wql | 92 Wkh |
//   94 Wkl | 96 Wvh ; Op 40..72 fp32 x2 (aliases dead slots) ; 98 ml.

typedef _Float16 half4 __attribute__((ext_vector_type(4)));
typedef _Float16 half8 __attribute__((ext_vector_type(8)));
typedef float floatx4 __attribute__((ext_vector_type(4)));

#define MFMA_F16(a, b, c) __builtin_amdgcn_mfma_f32_16x16x32_f16((a), (b), (c), 0, 0, 0)

constexpr int SEQ = 2048;
constexpr int DM = 1024;
constexpr int NH = 16;
constexpr int HD = 64;
// 64 * log2(e): fold score scale + base-2 conversion into Q projection
constexpr float QSCALE = 92.33248261689366f;

// async 16B/lane global->LDS copy; LDS dest = wave-uniform base + lane*16
__device__ __forceinline__ void gl2lds16(const _Float16* g, _Float16* l) {
  __builtin_amdgcn_global_load_lds(
      (const __attribute__((address_space(1))) void*)g,
      (__attribute__((address_space(3))) void*)l, 16, 0, 0);
}

__device__ inline void split4(const float4 f, half4& h, half4& l) {
  h[0] = (_Float16)f.x; l[0] = (_Float16)(f.x - (float)h[0]);
  h[1] = (_Float16)f.y; l[1] = (_Float16)(f.y - (float)h[1]);
  h[2] = (_Float16)f.z; l[2] = (_Float16)(f.z - (float)h[2]);
  h[3] = (_Float16)f.w; l[3] = (_Float16)(f.w - (float)h[3]);
}

// ---------------- fused convert: all six fp32 tensors -> fp16 hi (+lo) ------
__global__ __launch_bounds__(256) void convert_all(
    const float* __restrict__ q, const float* __restrict__ k,
    const float* __restrict__ v, const float* __restrict__ Wq,
    const float* __restrict__ Wk, const float* __restrict__ Wv,
    _Float16* __restrict__ xq_h, _Float16* __restrict__ xq_l,
    _Float16* __restrict__ xk_h, _Float16* __restrict__ xk_l,
    _Float16* __restrict__ xv_h,
    _Float16* __restrict__ Wqh, _Float16* __restrict__ Wql,
    _Float16* __restrict__ Wkh, _Float16* __restrict__ Wkl,
    _Float16* __restrict__ Wvh)
{
  const int bid = blockIdx.x;
  const float* src; _Float16* dh; _Float16* dl; int do_lo, i0;
  if (bid < 4096)       { src = q;  dh = xq_h; dl = xq_l; do_lo = 1; i0 = bid; }
  else if (bid < 8192)  { src = k;  dh = xk_h; dl = xk_l; do_lo = 1; i0 = bid - 4096; }
  else if (bid < 12288) { src = v;  dh = xv_h; dl = xv_h; do_lo = 0; i0 = bid - 8192; }
  else if (bid < 13312) { src = Wq; dh = Wqh;  dl = Wql;  do_lo = 1; i0 = bid - 12288; }
  else if (bid < 14336) { src = Wk; dh = Wkh;  dl = Wkl;  do_lo = 1; i0 = bid - 13312; }
  else                  { src = Wv; dh = Wvh;  dl = Wvh;  do_lo = 0; i0 = bid - 14336; }
  const int idx = i0 * 256 + threadIdx.x;
  float4 f = ((const float4*)src)[idx];
  half4 h, l; split4(f, h, l);
  *(half4*)(dh + (size_t)idx * 4) = h;
  if (do_lo) *(half4*)(dl + (size_t)idx * 4) = l;
}

// ---------------- fused projection GEMMs: y = A @ B^T (pre-converted fp16) --
// 128x128 tile, BK=64, global_load_lds staging, single-buffered (64 KiB LDS ->
// 2 blocks/CU). Grid (32,8,3): z selects {Q,K,V}. Q/K: 3-term split-fp16,
// scalar hi/lo epilogue. V: single-term, epilogue writes vhT DIRECTLY in the
// flash-permuted transposed layout (half4 stores).
__global__ __launch_bounds__(256, 1) void proj3_kernel(
    const _Float16* __restrict__ xq_h, const _Float16* __restrict__ xq_l,
    const _Float16* __restrict__ xk_h, const _Float16* __restrict__ xk_l,
    const _Float16* __restrict__ xv_h,
    const _Float16* __restrict__ Wqh, const _Float16* __restrict__ Wql,
    const _Float16* __restrict__ Wkh, const _Float16* __restrict__ Wkl,
    const _Float16* __restrict__ Wvh,
    _Float16* __restrict__ qh_hi, _Float16* __restrict__ qh_lo,
    _Float16* __restrict__ kh_hi, _Float16* __restrict__ kh_lo,
    _Float16* __restrict__ vhT)
{
  __shared__ __align__(16) _Float16 Ahs[128][64];
  __shared__ __align__(16) _Float16 Als[128][64];
  __shared__ __align__(16) _Float16 Bhs[128][64];
  __shared__ __align__(16) _Float16 Bls[128][64];

  const int z = blockIdx.z;
  const _Float16 *Ahg, *Alg, *Bhg, *Blg;
  _Float16 *yh, *yl;
  float scale; int three;
  if (z == 0)      { Ahg = xq_h; Alg = xq_l; Bhg = Wqh; Blg = Wql;
                     yh = qh_hi; yl = qh_lo; scale = QSCALE; three = 1; }
  else if (z == 1) { Ahg = xk_h; Alg = xk_l; Bhg = Wkh; Blg = Wkl;
                     yh = kh_hi; yl = kh_lo; scale = 1.0f; three = 1; }
  else             { Ahg = xv_h; Alg = xv_h; Bhg = Wvh; Blg = Wvh;
                     yh = vhT;   yl = vhT;   scale = 1.0f; three = 0; }

  const int tid = threadIdx.x;
  const int bm = blockIdx.x;          // 0..31
  const int bn = blockIdx.y;          // 0..7
  const int lane = tid & 63, l15 = lane & 15, quad = lane >> 4;
  const int w = tid >> 6, wm = w >> 1, wn = w & 1;

  // staging: wave w stages groups g = 4w+i (8 rows x 1 KiB each) of each array.
  // lane L: row-in-group = L>>3, fetches logical chunk (L&7)^(L>>3) -> XOR image.
  const int r8 = lane >> 3;
  const int cp8 = (((lane & 7) ^ r8)) * 8;    // half offset within row
  int grow[4]; _Float16* la[4]; _Float16* lal[4]; _Float16* lb[4]; _Float16* lbl[4];
  #pragma unroll
  for (int i = 0; i < 4; i++) {
    const int g = w * 4 + i;
    grow[i] = g * 8 + r8;                     // row 0..127 (per-lane)
    la[i]  = &Ahs[0][0] + g * 512;            // wave-uniform LDS bases
    lal[i] = &Als[0][0] + g * 512;
    lb[i]  = &Bhs[0][0] + g * 512;
    lbl[i] = &Bls[0][0] + g * 512;
  }

  floatx4 acc[4][4];
  #pragma unroll
  for (int mt = 0; mt < 4; mt++)
    #pragma unroll
    for (int nt = 0; nt < 4; nt++)
      acc[mt][nt] = (floatx4){0.f, 0.f, 0.f, 0.f};

  for (int kk = 0; kk < DM; kk += 64) {
    __syncthreads();                          // prior tile's reads complete
    #pragma unroll
    for (int i = 0; i < 4; i++) {
      const size_t ga = (size_t)(bm * 128 + grow[i]) * DM + kk + cp8;
      const size_t gb = (size_t)(bn * 128 + grow[i]) * DM + kk + cp8;
      gl2lds16(Ahg + ga, la[i]);
      gl2lds16(Bhg + gb, lb[i]);
      if (three) {
        gl2lds16(Alg + ga, lal[i]);
        gl2lds16(Blg + gb, lbl[i]);
      }
    }
    __syncthreads();                          // vmcnt(0) drain: tile visible

    #pragma unroll
    for (int kc = 0; kc < 2; kc++) {
      const int swz = ((kc * 4 + quad) ^ (l15 & 7)) * 8;
      half8 ah[4], bh_[4], al[4], bl[4];
      #pragma unroll
      for (int t = 0; t < 4; t++) {
        ah[t]  = *(const half8*)&Ahs[wm * 64 + t * 16 + l15][swz];
        bh_[t] = *(const half8*)&Bhs[wn * 64 + t * 16 + l15][swz];
        if (three) {
          al[t] = *(const half8*)&Als[wm * 64 + t * 16 + l15][swz];
          bl[t] = *(const half8*)&Bls[wn * 64 + t * 16 + l15][swz];
        }
      }
      if (three) {
        #pragma unroll
        for (int mt = 0; mt < 4; mt++)
          #pragma unroll
          for (int nt = 0; nt < 4; nt++) {
            floatx4 t0 = MFMA_F16(ah[mt], bh_[nt], acc[mt][nt]);
            t0 = MFMA_F16(ah[mt], bl[nt], t0);
            acc[mt][nt] = MFMA_F16(al[mt], bh_[nt], t0);
          }
      } else {
        #pragma unroll
        for (int mt = 0; mt < 4; mt++)
          #pragma unroll
          for (int nt = 0; nt < 4; nt++)
            acc[mt][nt] = MFMA_F16(ah[mt], bh_[nt], acc[mt][nt]);
      }
    }
  }

  if (three) {
    // Q/K epilogue: scalar hi/lo stores to [b,h,s,d]
    #pragma unroll
    for (int mt = 0; mt < 4; mt++)
      #pragma unroll
      for (int nt = 0; nt < 4; nt++)
        #pragma unroll
        for (int r = 0; r < 4; r++) {
          int gm = bm * 128 + wm * 64 + mt * 16 + quad * 4 + r;   // (b,s)
          int gn = bn * 128 + wn * 64 + nt * 16 + l15;            // h*64+d
          int b = gm >> 11, s = gm & 2047;
          int h = gn >> 6, d = gn & 63;
          size_t idx = ((size_t)(b * NH + h) * SEQ + s) * HD + d;
          float val = acc[mt][nt][r] * scale;
          _Float16 hi = (_Float16)val;
          yh[idx] = hi;
          yl[idx] = (_Float16)(val - (float)hi);
        }
  } else {
    // V epilogue: write vhT [bh][d][perm(s)] directly.
    // s = sbase + mt*16 + quad*4 + r ; s%32 = (mt&1)*16 + quad*4 + r
    // perm: 16a+4q+b -> 8q+4a+b, so pos = sbase + (mt>>1)*32 + quad*8 + (mt&1)*4 + r
    // r=0..3 contiguous -> one aligned half4 per (mt,nt).
    const int b = bm >> 4;
    const int h = bn * 2 + wn;
    const int bh = b * NH + h;
    const int sbase = (bm & 15) * 128 + wm * 64;
    _Float16* vt = vhT + (size_t)bh * HD * SEQ;
    #pragma unroll
    for (int mt = 0; mt < 4; mt++) {
      const int pos = sbase + (mt >> 1) * 32 + quad * 8 + (mt & 1) * 4;
      #pragma unroll
      for (int nt = 0; nt < 4; nt++) {
        const int d = nt * 16 + l15;
        half4 hv;
        hv[0] = (_Float16)acc[mt][nt][0];
        hv[1] = (_Float16)acc[mt][nt][1];
        hv[2] = (_Float16)acc[mt][nt][2];
        hv[3] = (_Float16)acc[mt][nt][3];
        *(half4*)(vt + (size_t)d * SEQ + pos) = hv;
      }
    }
  }
}

// ---------------- flash attention v12: split-K x2 + 2-phase stage ----------
// 1-D grid 1024; bh = (id&7) + 8*((id>>3)&3) pins each bh's K/V to one XCD L2.
// 4 waves, 32 q/wave. K hi/lo double-buffered, V single (40960 B LDS).
// Per kt: barrier -> stage V(kt)+K(kt+1) -> QK^T+softmax+pack -> barrier(drain)
// -> av reads + PV.
__global__ __launch_bounds__(256, 4) void flash_kernel(
    const _Float16* __restrict__ qh_hi, const _Float16* __restrict__ qh_lo,
    const _Float16* __restrict__ kh_hi, const _Float16* __restrict__ kh_lo,
    const _Float16* __restrict__ vhT, float* __restrict__ Op, float2* __restrict__ ml)
{
  __shared__ __align__(16) _Float16 Kh[2][64][64];
  __shared__ __align__(16) _Float16 Kl[2][64][64];
  __shared__ __align__(16) _Float16 Vt[64][64];   // [d][permuted key]

  const int id = blockIdx.x;
  const int seq_ = id >> 3;
  const int bh = (id & 7) + 8 * (seq_ & 3);       // 0..31, pinned to XCD id&7
  const int rem = seq_ >> 2;
  const int qb = rem & 15;                        // 0..15
  const int kh = rem >> 4;                        // 0..1
  const int tid = threadIdx.x;
  const int wq = tid >> 6;
  const int lane = tid & 63, l15 = lane & 15, quad = lane >> 4;

  const size_t bh_off = (size_t)bh * SEQ * HD;
  const _Float16* __restrict__ kh_p = kh_hi + bh_off;
  const _Float16* __restrict__ kl_p = kh_lo + bh_off;
  const _Float16* __restrict__ vt_p = vhT + (size_t)bh * HD * SEQ;
  const int qrow0 = qb * 128 + wq * 32;

  // Q as B-operand fragments: lane holds n=q=l15, k=d=kc*32+quad*8+j
  half8 bqh[2][2], bql[2][2];         // [g][kc]
  #pragma unroll
  for (int g = 0; g < 2; g++) {
    const _Float16* qp_h = qh_hi + bh_off + (size_t)(qrow0 + g * 16 + l15) * HD;
    const _Float16* qp_l = qh_lo + bh_off + (size_t)(qrow0 + g * 16 + l15) * HD;
    #pragma unroll
    for (int kc = 0; kc < 2; kc++) {
      bqh[g][kc] = *(const half8*)(qp_h + kc * 32 + quad * 8);
      bql[g][kc] = *(const half8*)(qp_l + kc * 32 + quad * 8);
    }
  }

  // staging: wave wq covers groups 2wq, 2wq+1 per array (8 rows x 1 KiB each)
  const int r8 = lane >> 3;
  const int cp8 = ((lane & 7) ^ r8) * 8;

  float m_[2] = {-3.0e38f, -3.0e38f};
  float l_[2] = {0.f, 0.f};
  floatx4 Oacc[2][4];
  #pragma unroll
  for (int g = 0; g < 2; g++)
    #pragma unroll
    for (int nd = 0; nd < 4; nd++) Oacc[g][nd] = (floatx4){0.f, 0.f, 0.f, 0.f};

  const int kt0 = kh * 16;
  // prologue: stage K(kt0) into buffer 0
  {
    const int kbase = kt0 * 64;
    #pragma unroll
    for (int i = 0; i < 2; i++) {
      const int g = wq * 2 + i;
      const int r = g * 8 + r8;
      gl2lds16(kh_p + (size_t)(kbase + r) * HD + cp8, &Kh[0][0][0] + g * 512);
      gl2lds16(kl_p + (size_t)(kbase + r) * HD + cp8, &Kl[0][0][0] + g * 512);
    }
  }

  for (int kt = kt0; kt < kt0 + 16; kt++) {
    const int cur = kt & 1;                     // kt0 even -> prologue in buf 0
    const int kbase = kt * 64;
    __syncthreads();            // K(kt) visible; Vt free; Kbuf[cur^1] free

    // stage V(kt) and prefetch K(kt+1); both drain at the mid barrier below
    #pragma unroll
    for (int i = 0; i < 2; i++) {
      const int g = wq * 2 + i;
      const int r = g * 8 + r8;
      gl2lds16(vt_p + (size_t)r * SEQ + kbase + cp8, &Vt[0][0] + g * 512);
    }
    if (kt + 1 < kt0 + 16) {
      const int kb2 = (kt + 1) * 64, nxt = cur ^ 1;
      #pragma unroll
      for (int i = 0; i < 2; i++) {
        const int g = wq * 2 + i;
        const int r = g * 8 + r8;
        gl2lds16(kh_p + (size_t)(kb2 + r) * HD + cp8, &Kh[nxt][0][0] + g * 512);
        gl2lds16(kl_p + (size_t)(kb2 + r) * HD + cp8, &Kl[nxt][0][0] + g * 512);
      }
    }

    // S^T = K·Q^T (3-term split fp16), both q-groups share K fragments
    floatx4 sacc[2][4];
    const int r7 = l15 & 7;
    #pragma unroll
    for (int nt = 0; nt < 4; nt++) {
      half8 akh0 = *(const half8*)&Kh[cur][nt * 16 + l15][((0 * 4 + quad) ^ r7) * 8];
      half8 akh1 = *(const half8*)&Kh[cur][nt * 16 + l15][((1 * 4 + quad) ^ r7) * 8];
      half8 akl0 = *(const half8*)&Kl[cur][nt * 16 + l15][((0 * 4 + quad) ^ r7) * 8];
      half8 akl1 = *(const half8*)&Kl[cur][nt * 16 + l15][((1 * 4 + quad) ^ r7) * 8];
      #pragma unroll
      for (int g = 0; g < 2; g++) {
        floatx4 s4 = (floatx4){0.f, 0.f, 0.f, 0.f};
        s4 = MFMA_F16(akh0, bqh[g][0], s4);
        s4 = MFMA_F16(akh1, bqh[g][1], s4);
        s4 = MFMA_F16(akh0, bql[g][0], s4);
        s4 = MFMA_F16(akh1, bql[g][1], s4);
        s4 = MFMA_F16(akl0, bqh[g][0], s4);
        s4 = MFMA_F16(akl1, bqh[g][1], s4);
        sacc[g][nt] = s4;
      }
    }

    // online softmax + P pack for BOTH q-groups (before the drain barrier)
    float alpha2[2];
    half8 bp8g[2][2];
    #pragma unroll
    for (int g = 0; g < 2; g++) {
      float rmax = sacc[g][0][0];
      #pragma unroll
      for (int nt = 0; nt < 4; nt++)
        #pragma unroll
        for (int r = 0; r < 4; r++) rmax = fmaxf(rmax, sacc[g][nt][r]);
      rmax = fmaxf(rmax, __shfl_xor(rmax, 16, 64));
      rmax = fmaxf(rmax, __shfl_xor(rmax, 32, 64));
      const float mnew = fmaxf(m_[g], rmax);
      alpha2[g] = exp2f(m_[g] - mnew);
      m_[g] = mnew;

      float rsum = 0.f;
      #pragma unroll
      for (int nt = 0; nt < 4; nt++)
        #pragma unroll
        for (int r = 0; r < 4; r++) {
          float p = exp2f(sacc[g][nt][r] - mnew);
          sacc[g][nt][r] = p;
          rsum += p;
        }
      rsum += __shfl_xor(rsum, 16, 64);
      rsum += __shfl_xor(rsum, 32, 64);
      l_[g] = l_[g] * alpha2[g] + rsum;

      // P pack for PV B-operand: bp8g[g][kc][j] = p[2kc + (j>>2)][j&3] (in-lane)
      #pragma unroll
      for (int kc = 0; kc < 2; kc++)
        #pragma unroll
        for (int j = 0; j < 8; j++)
          bp8g[g][kc][j] = (_Float16)sacc[g][2 * kc + (j >> 2)][j & 3];
    }

    __syncthreads();            // V(kt) + K(kt+1) drained & visible

    // V A-fragments (permuted image), shared by both q-groups
    half8 av[4][2];
    #pragma unroll
    for (int nd = 0; nd < 4; nd++) {
      av[nd][0] = *(const half8*)&Vt[nd * 16 + l15][((0 * 4 + quad) ^ r7) * 8];
      av[nd][1] = *(const half8*)&Vt[nd * 16 + l15][((1 * 4 + quad) ^ r7) * 8];
    }

    #pragma unroll
    for (int g = 0; g < 2; g++) {
      #pragma unroll
      for (int nd = 0; nd < 4; nd++) {
        Oacc[g][nd][0] *= alpha2[g]; Oacc[g][nd][1] *= alpha2[g];
        Oacc[g][nd][2] *= alpha2[g]; Oacc[g][nd][3] *= alpha2[g];
        Oacc[g][nd] = MFMA_F16(av[nd][0], bp8g[g][0], Oacc[g][nd]);
        Oacc[g][nd] = MFMA_F16(av[nd][1], bp8g[g][1], Oacc[g][nd]);
      }
    }
  }

  // epilogue: unnormalized O^T partial + (m,l)
  const size_t fqbase = (size_t)bh * SEQ + qrow0;
  #pragma unroll
  for (int g = 0; g < 2; g++) {
    const size_t fq = fqbase + g * 16 + l15;
    float* ob = Op + ((size_t)kh * 65536 + fq) * HD;
    #pragma unroll
    for (int nd = 0; nd < 4; nd++) {
      float4 vv;
      vv.x = Oacc[g][nd][0]; vv.y = Oacc[g][nd][1];
      vv.z = Oacc[g][nd][2]; vv.w = Oacc[g][nd][3];
      *(float4*)(ob + nd * 16 + quad * 4) = vv;
    }
    if (quad == 0) ml[kh * 65536 + fq] = make_float2(m_[g], l_[g]);
  }
}

// ---------------- merge the two split-K partials ----------------
__global__ __launch_bounds__(256) void merge_kernel(const float* __restrict__ Op,
                                                    const float2* __restrict__ ml,
                                                    float* __restrict__ out)
{
  const int tid = threadIdx.x;
  const int fq = blockIdx.x * 64 + (tid >> 2);
  const int dp = (tid & 3) * 16;
  float2 m0 = ml[fq], m1 = ml[65536 + fq];
  float M = fmaxf(m0.x, m1.x);
  float w0 = exp2f(m0.x - M), w1 = exp2f(m1.x - M);
  float rinv = 1.0f / (m0.y * w0 + m1.y * w1);
  int bh = fq >> 11, s = fq & 2047, b = bh >> 4, h = bh & 15;
  float* ob = out + ((size_t)(b * SEQ + s)) * DM + h * HD + dp;
  const float* p0 = Op + (size_t)fq * HD + dp;
  const float* p1 = p0 + (size_t)65536 * HD;
  #pragma unroll
  for (int j = 0; j < 4; j++) {
    float4 a = *(const float4*)(p0 + 4 * j);
    float4 c = *(const float4*)(p1 + 4 * j);
    float4 r;
    r.x = (a.x * w0 + c.x * w1) * rinv;
    r.y = (a.y * w0 + c.y * w1) * rinv;
    r.z = (a.z * w0 + c.z * w1) * rinv;
    r.w = (a.w * w0 + c.w * w1) * rinv;
    *(float4*)(ob + 4 * j) = r;
  }
}

extern "C" void kernel_launch(void* const* d_in, const int* in_sizes, int n_in,
                              void* d_out, int out_size, void* d_ws, size_t ws_size,
                              hipStream_t stream) {
  const float* q  = (const float*)d_in[0];
  const float* k  = (const float*)d_in[1];
  const float* v  = (const float*)d_in[2];
  const float* Wq = (const float*)d_in[3];
  const float* Wk = (const float*)d_in[4];
  const float* Wv = (const float*)d_in[5];
  float* out = (float*)d_out;

  char* W = (char*)d_ws;
  const size_t MiB = 1ull << 20;
  _Float16* qh_hi = (_Float16*)(W + 0 * MiB);
  _Float16* qh_lo = (_Float16*)(W + 8 * MiB);
  _Float16* kh_hi = (_Float16*)(W + 16 * MiB);
  _Float16* kh_lo = (_Float16*)(W + 24 * MiB);
  _Float16* vhT   = (_Float16*)(W + 32 * MiB);
  _Float16* xq_h  = (_Float16*)(W + 48 * MiB);  // dead after proj3
  _Float16* xq_l  = (_Float16*)(W + 56 * MiB);
  _Float16* xk_h  = (_Float16*)(W + 64 * MiB);
  _Float16* xk_l  = (_Float16*)(W + 72 * MiB);
  _Float16* xv_h  = (_Float16*)(W + 80 * MiB);
  _Float16* Wqh   = (_Float16*)(W + 88 * MiB);
  _Float16* Wql   = (_Float16*)(W + 90 * MiB);
  _Float16* Wkh   = (_Float16*)(W + 92 * MiB);
  _Float16* Wkl   = (_Float16*)(W + 94 * MiB);
  _Float16* Wvh   = (_Float16*)(W + 96 * MiB);
  float*    Op    = (float*)  (W + 40 * MiB);   // 2 x 16 MiB, aliases dead slots
  float2*   mlp   = (float2*) (W + 98 * MiB);   // 1 MiB; total 99 MiB

  convert_all<<<15360, 256, 0, stream>>>(q, k, v, Wq, Wk, Wv,
                                         xq_h, xq_l, xk_h, xk_l, xv_h,
                                         Wqh, Wql, Wkh, Wkl, Wvh);
  proj3_kernel<<<dim3(32, 8, 3), 256, 0, stream>>>(
      xq_h, xq_l, xk_h, xk_l, xv_h, Wqh, Wql, Wkh, Wkl, Wvh,
      qh_hi, qh_lo, kh_hi, kh_lo, vhT);
  flash_kernel<<<1024, 256, 0, stream>>>(qh_hi, qh_lo, kh_hi, kh_lo, vhT, Op, mlp);
  merge_kernel<<<1024, 256, 0, stream>>>(Op, mlp, out);
}